// Round 1
// baseline (7437.640 us; speedup 1.0000x reference)
//
#include <hip/hip_runtime.h>
#include <math.h>

#define S_  5
#define B_  2
#define C_  128
#define N_  576
#define SB  10
#define NPAIR 40
#define C2  256

// ---------------------------------------------------------------- conv3x3 x3
__global__ __launch_bounds__(576) void conv3x3_3way(
    const float* __restrict__ in,
    const float* __restrict__ wf, const float* __restrict__ bf,
    const float* __restrict__ wh, const float* __restrict__ bh,
    const float* __restrict__ wl, const float* __restrict__ bl,
    float* __restrict__ oft, float* __restrict__ oht, float* __restrict__ olt)
{
    int img = blockIdx.x;
    int oc3 = blockIdx.y;          // 0..383
    int which = oc3 >> 7;
    int co = oc3 & 127;
    const float* w; const float* bias; float* out;
    if (which == 0)      { w = wf; bias = bf; out = oft; }
    else if (which == 1) { w = wh; bias = bh; out = oht; }
    else                 { w = wl; bias = bl; out = olt; }

    __shared__ float sp[26*26];
    int t = threadIdx.x;
    int ph = t / 24, pw = t % 24;
    for (int i = t; i < 26*26; i += 576) sp[i] = 0.f;   // border stays 0

    float acc = bias[co];
    const float* wr = w + (size_t)co * (C_*9);
    const float* ip = in + (size_t)img * C_ * N_;
    int base   = ph*26 + pw;
    int center = (ph+1)*26 + (pw+1);
    for (int ci = 0; ci < C_; ++ci) {
        __syncthreads();
        sp[center] = ip[ci*N_ + t];
        __syncthreads();
        const float* wk = wr + ci*9;
        acc += wk[0]*sp[base]    + wk[1]*sp[base+1]  + wk[2]*sp[base+2]
             + wk[3]*sp[base+26] + wk[4]*sp[base+27] + wk[5]*sp[base+28]
             + wk[6]*sp[base+52] + wk[7]*sp[base+53] + wk[8]*sp[base+54];
    }
    out[((size_t)img*C_ + co)*N_ + t] = acc;
}

// ---------------------------------------------------------------- yt = Wc @ h
__global__ __launch_bounds__(576) void yt_kernel(
    const float* __restrict__ h, const float* __restrict__ Wc, float* __restrict__ yt)
{
    int img = blockIdx.x, co = blockIdx.y, t = threadIdx.x;
    const float* wrow = Wc + (size_t)co * C_;
    const float* hp = h + (size_t)img * C_ * N_;
    float acc = 0.f;
    for (int d = 0; d < C_; ++d) acc += wrow[d] * hp[d*N_ + t];
    yt[((size_t)img*C_ + co)*N_ + t] = acc;
}

// ------------------------------------------------- fused attention (both paths)
// mode 0 (intra): pair p = img(s,b); O = scale*ctx + addsrc
// mode 1 (inter): pair p -> (i,j!=i,b); O = ctx
__global__ __launch_bounds__(576) void attn_kernel(
    const float* __restrict__ Q, const float* __restrict__ K, const float* __restrict__ V,
    float* __restrict__ O, const float* __restrict__ addsrc,
    const float* __restrict__ scale_ptr, int mode)
{
    __shared__ float qs[C_*16];     // [c][r]
    __shared__ float E[16*577];     // score/prob tile, stride 577
    int t = threadIdx.x;
    int n0 = blockIdx.x * 16;
    int p = blockIdx.y;
    int qimg, kimg, vimg;
    if (mode == 0) { qimg = kimg = vimg = p; }
    else {
        int b = p & 1; int ij = p >> 1; int i = ij >> 2; int jj = ij & 3;
        int j = jj + (jj >= i ? 1 : 0);
        qimg = i*B_ + b; kimg = j*B_ + b; vimg = kimg;
    }
    const float* Qp = Q + (size_t)qimg * C_ * N_;
    const float* Kp = K + (size_t)kimg * C_ * N_;
    const float* Vp = V + (size_t)vimg * C_ * N_;

    for (int idx = t; idx < C_*16; idx += 576) {
        int c = idx >> 4, r = idx & 15;
        qs[idx] = Qp[c*N_ + n0 + r];
    }
    __syncthreads();

    // phase 1: scores column m = t
    {
        float acc[16];
        #pragma unroll
        for (int r = 0; r < 16; ++r) acc[r] = 0.f;
        int m = t;
        for (int c = 0; c < C_; ++c) {
            float kv = Kp[c*N_ + m];
            #pragma unroll
            for (int r = 0; r < 16; ++r) acc[r] += qs[c*16 + r] * kv;
        }
        #pragma unroll
        for (int r = 0; r < 16; ++r) E[r*577 + m] = acc[r];
    }
    __syncthreads();

    // phase 2: row softmax (wave w handles rows w, w+9)
    {
        int wave = t >> 6, lane = t & 63;
        for (int r = wave; r < 16; r += 9) {
            float v[9];
            float mx = -1e30f;
            #pragma unroll
            for (int k = 0; k < 9; ++k) { v[k] = E[r*577 + lane + 64*k]; mx = fmaxf(mx, v[k]); }
            #pragma unroll
            for (int off = 32; off > 0; off >>= 1) mx = fmaxf(mx, __shfl_xor(mx, off));
            float sum = 0.f;
            #pragma unroll
            for (int k = 0; k < 9; ++k) { v[k] = __expf(v[k] - mx); sum += v[k]; }
            #pragma unroll
            for (int off = 32; off > 0; off >>= 1) sum += __shfl_xor(sum, off);
            float inv = 1.f / sum;
            #pragma unroll
            for (int k = 0; k < 9; ++k) E[r*577 + lane + 64*k] = v[k] * inv;
        }
    }
    __syncthreads();

    // phase 3: O[:, n0:n0+16] = V @ P^T  (threads 0..511: c = t>>2, rows 4*(t&3)..)
    if (t < 512) {
        int c = t >> 2, rr = t & 3;
        float acc[4] = {0.f, 0.f, 0.f, 0.f};
        const float* vrow = Vp + (size_t)c * N_;
        for (int m = 0; m < N_; ++m) {
            float vv = vrow[m];
            #pragma unroll
            for (int k = 0; k < 4; ++k) acc[k] += vv * E[(rr*4 + k)*577 + m];
        }
        float scale = scale_ptr ? scale_ptr[0] : 1.f;
        float* op = O + ((size_t)p * C_ + c) * N_ + n0 + rr*4;
        if (addsrc) {
            const float* ap = addsrc + ((size_t)p * C_ + c) * N_ + n0 + rr*4;
            #pragma unroll
            for (int k = 0; k < 4; ++k) op[k] = scale * acc[k] + ap[k];
        } else {
            #pragma unroll
            for (int k = 0; k < 4; ++k) op[k] = scale * acc[k];
        }
    }
}

// ------------------------------------- window sums for analytic gate-conv mean
__global__ __launch_bounds__(64) void wsum_kernel(
    const float* __restrict__ mji, float* __restrict__ wsum)
{
    int pair = blockIdx.x, ci = blockIdx.y, lane = threadIdx.x;
    const float* p = mji + ((size_t)pair*C_ + ci)*N_;
    float T=0, R0=0, R23=0, Cl=0, Cr=0, c00=0, c0w=0, ch0=0, chw=0;
    for (int i = lane; i < N_; i += 64) {
        float v = p[i];
        int r = i / 24, cc = i % 24;
        T += v;
        if (r == 0)  R0  += v;
        if (r == 23) R23 += v;
        if (cc == 0)  Cl += v;
        if (cc == 23) Cr += v;
        if (i == 0)   c00 = v;
        if (i == 23)  c0w = v;
        if (i == 552) ch0 = v;
        if (i == 575) chw = v;
    }
    #pragma unroll
    for (int off = 32; off > 0; off >>= 1) {
        T  += __shfl_xor(T, off);  R0 += __shfl_xor(R0, off);  R23 += __shfl_xor(R23, off);
        Cl += __shfl_xor(Cl, off); Cr += __shfl_xor(Cr, off);
        c00 += __shfl_xor(c00, off); c0w += __shfl_xor(c0w, off);
        ch0 += __shfl_xor(ch0, off); chw += __shfl_xor(chw, off);
    }
    if (lane == 0) {
        // tap (ky,kx): dy=ky-1, dx=kx-1. Window sum = T - excluded row - excluded col + corner
        float rowsub[3] = {R23, 0.f, R0};
        float colsub[3] = {Cr,  0.f, Cl};
        float corner[9] = {chw, 0.f, ch0,  0.f, 0.f, 0.f,  c0w, 0.f, c00};
        float* o = wsum + ((size_t)pair*C_ + ci)*9;
        #pragma unroll
        for (int ky = 0; ky < 3; ++ky)
            #pragma unroll
            for (int kx = 0; kx < 3; ++kx)
                o[ky*3+kx] = T - rowsub[ky] - colsub[kx] + corner[ky*3+kx];
    }
}

// ------------------------------------------------------------- gate g per (pair, co)
__global__ __launch_bounds__(128) void g_kernel(
    const float* __restrict__ wsum, const float* __restrict__ Wg,
    const float* __restrict__ Wgb, float* __restrict__ g)
{
    __shared__ float sw[C_*9];
    int pair = blockIdx.x; int co = threadIdx.x;
    for (int i = co; i < C_*9; i += 128) sw[i] = wsum[(size_t)pair*C_*9 + i];
    __syncthreads();
    const float* w = Wg + (size_t)co * C_ * 9;
    float acc = 0.f;
    for (int i = 0; i < C_*9; ++i) acc += w[i] * sw[i];
    float m = acc * (1.f/576.f) + Wgb[co];
    g[pair*C_ + co] = 1.f / (1.f + __expf(-m));
}

// ------------------------------------------------- msg = intra*eii + inter*inter
__global__ void msg_kernel(
    const float* __restrict__ eii, const float* __restrict__ mji,
    const float* __restrict__ g, const float* __restrict__ bn_gamma,
    const float* __restrict__ bn_beta, const float* __restrict__ intra_w,
    const float* __restrict__ inter_w, float* __restrict__ msg)
{
    int e = blockIdx.x * blockDim.x + threadIdx.x;
    if (e >= SB*C_*N_) return;
    int n = e % N_;
    int c = (e / N_) % C_;
    int img = e / (N_*C_);
    int s = img >> 1, b = img & 1;
    float scale = bn_gamma[c] * rsqrtf(1.f + 1e-5f);
    float acc = 0.f;
    #pragma unroll
    for (int jj = 0; jj < 4; ++jj) {
        int pidx = (s*4 + jj)*2 + b;
        acc += g[pidx*C_ + c] * mji[((size_t)pidx*C_ + c)*N_ + n];
    }
    float inter = scale * acc + 4.f * bn_beta[c];
    msg[e] = intra_w[0] * eii[e] + inter_w[0] * inter;
}

// --------------------------------------------------- conv5x5 on concat(A,Bsrc)
__global__ __launch_bounds__(576) void conv5x5_kernel(
    const float* __restrict__ A, const float* __restrict__ Bsrc,
    const float* __restrict__ w, const float* __restrict__ bias,
    float* __restrict__ out, int cout, int act)
{
    int img = blockIdx.x, co = blockIdx.y;
    __shared__ float sp[28*28];
    int t = threadIdx.x;
    int ph = t / 24, pw = t % 24;
    for (int i = t; i < 28*28; i += 576) sp[i] = 0.f;
    float acc = bias[co];
    const float* wr = w + (size_t)co * (C2*25);
    int base   = ph*28 + pw;
    int center = (ph+2)*28 + (pw+2);
    for (int ci = 0; ci < C2; ++ci) {
        const float* src = (ci < C_) ? (A + ((size_t)img*C_ + ci)*N_)
                                     : (Bsrc + ((size_t)img*C_ + (ci - C_))*N_);
        __syncthreads();
        sp[center] = src[t];
        __syncthreads();
        const float* wk = wr + ci*25;
        #pragma unroll
        for (int ky = 0; ky < 5; ++ky) {
            int o = base + ky*28;
            acc += wk[ky*5+0]*sp[o]   + wk[ky*5+1]*sp[o+1] + wk[ky*5+2]*sp[o+2]
                 + wk[ky*5+3]*sp[o+3] + wk[ky*5+4]*sp[o+4];
        }
    }
    acc = (act == 1) ? (1.f / (1.f + __expf(-acc))) : tanhf(acc);
    out[((size_t)img*cout + co)*N_ + t] = acc;
}

// ----------------------------------------------------------------- elementwise
__global__ void rhb_kernel(const float* __restrict__ zr, const float* __restrict__ h,
                           float* __restrict__ rhb)
{
    int e = blockIdx.x * blockDim.x + threadIdx.x;
    if (e >= SB*C_*N_) return;
    int n = e % N_;
    int c = (e / N_) % C_;
    int img = e / (N_*C_);
    float r = zr[((size_t)img*C2 + C_ + c)*N_ + n];
    rhb[e] = r * h[e];
}

__global__ void update_kernel(const float* __restrict__ zr, const float* __restrict__ hhat,
                              const float* __restrict__ h, float* __restrict__ out)
{
    int e = blockIdx.x * blockDim.x + threadIdx.x;
    if (e >= SB*C_*N_) return;
    int n = e % N_;
    int c = (e / N_) % C_;
    int img = e / (N_*C_);
    float z = zr[((size_t)img*C2 + c)*N_ + n];
    out[e] = (2.f - z) * h[e] + z * hhat[e];   // h_new + hb
}

// ------------------------------------------------------------------- launcher
extern "C" void kernel_launch(void* const* d_in, const int* in_sizes, int n_in,
                              void* d_out, int out_size, void* d_ws, size_t ws_size,
                              hipStream_t stream)
{
    const float* x      = (const float*)d_in[0];
    const float* Wf_w   = (const float*)d_in[1];
    const float* Wf_b   = (const float*)d_in[2];
    const float* Wh_w   = (const float*)d_in[3];
    const float* Wh_b   = (const float*)d_in[4];
    const float* Wl_w   = (const float*)d_in[5];
    const float* Wl_b   = (const float*)d_in[6];
    const float* alpha  = (const float*)d_in[7];
    const float* Wc     = (const float*)d_in[8];
    const float* Wg_w   = (const float*)d_in[9];
    const float* Wg_b   = (const float*)d_in[10];
    const float* bng    = (const float*)d_in[11];
    const float* bnb    = (const float*)d_in[12];
    const float* zr_w   = (const float*)d_in[13];
    const float* zr_b   = (const float*)d_in[14];
    const float* gh_w   = (const float*)d_in[15];
    const float* gh_b   = (const float*)d_in[16];
    const float* intraw = (const float*)d_in[17];
    const float* interw = (const float*)d_in[18];
    float* outp = (float*)d_out;

    float* ws = (float*)d_ws;
    const size_t SZ = (size_t)SB * C_ * N_;     // 737280
    float* hbuf  = ws; ws += SZ;
    float* ft    = ws; ws += SZ;
    float* ht    = ws; ws += SZ;
    float* lt    = ws; ws += SZ;
    float* eii   = ws; ws += SZ;
    float* yt    = ws; ws += SZ;
    float* msg   = ws; ws += SZ;
    float* rhb   = ws; ws += SZ;
    float* hhat  = ws; ws += SZ;
    float* mji   = ws; ws += (size_t)NPAIR * C_ * N_;
    float* zr    = ws; ws += (size_t)SB * C2 * N_;
    float* wsumb = ws; ws += (size_t)NPAIR * C_ * 9;
    float* gbuf  = ws; ws += (size_t)NPAIR * C_;

    const int NELEM = SB * C_ * N_;
    dim3 eb((NELEM + 255) / 256);

    const float* hcur = x;
    for (int it = 0; it < 3; ++it) {
        float* hout = (it == 2) ? outp : hbuf;
        conv3x3_3way<<<dim3(SB, 3*C_), 576, 0, stream>>>(hcur, Wf_w, Wf_b, Wh_w, Wh_b, Wl_w, Wl_b, ft, ht, lt);
        attn_kernel<<<dim3(36, SB), 576, 0, stream>>>(ft, ht, lt, eii, hcur, alpha, 0);
        yt_kernel<<<dim3(SB, C_), 576, 0, stream>>>(hcur, Wc, yt);
        attn_kernel<<<dim3(36, NPAIR), 576, 0, stream>>>(hcur, yt, hcur, mji, nullptr, nullptr, 1);
        wsum_kernel<<<dim3(NPAIR, C_), 64, 0, stream>>>(mji, wsumb);
        g_kernel<<<NPAIR, 128, 0, stream>>>(wsumb, Wg_w, Wg_b, gbuf);
        msg_kernel<<<eb, 256, 0, stream>>>(eii, mji, gbuf, bng, bnb, intraw, interw, msg);
        conv5x5_kernel<<<dim3(SB, C2), 576, 0, stream>>>(msg, hcur, zr_w, zr_b, zr, C2, 1);
        rhb_kernel<<<eb, 256, 0, stream>>>(zr, hcur, rhb);
        conv5x5_kernel<<<dim3(SB, C_), 576, 0, stream>>>(msg, rhb, gh_w, gh_b, hhat, C_, 2);
        update_kernel<<<eb, 256, 0, stream>>>(zr, hhat, hcur, hout);
        hcur = hout;
    }
}

// Round 2
// 2142.680 us; speedup vs baseline: 3.4712x; 3.4712x over previous
//
#include <hip/hip_runtime.h>
#include <math.h>

#define S_  5
#define B_  2
#define C_  128
#define N_  576
#define SB  10
#define NPAIR 40
#define C2  256

typedef short v8s __attribute__((ext_vector_type(8)));
typedef float v4f __attribute__((ext_vector_type(4)));

__device__ __forceinline__ unsigned short f2bf(float f) {
    union { float f; unsigned u; } v; v.f = f;
    unsigned r = (v.u + 0x7FFF + ((v.u >> 16) & 1)) >> 16;
    return (unsigned short)r;
}
__device__ __forceinline__ float bf2f(unsigned short h) {
    union { unsigned u; float f; } v; v.u = ((unsigned)h) << 16;
    return v.f;
}

// ------------------------------------------------------------------ weight packs
// Wp[co][tap*Cin+ci] (bf16) from W[co][ci][tap] (f32)
__global__ void pack3_kernel(const float* __restrict__ wf, const float* __restrict__ wh,
                             const float* __restrict__ wl, unsigned short* __restrict__ Wp3)
{
    int idx = blockIdx.x * 256 + threadIdx.x;
    if (idx >= 384 * 1152) return;
    int co = idx / 1152, k = idx % 1152;
    int tap = k >> 7, ci = k & 127;
    const float* w = (co < 128) ? wf : (co < 256) ? wh : wl;
    int c = co & 127;
    Wp3[idx] = f2bf(w[((size_t)c * 128 + ci) * 9 + tap]);
}
__global__ void pack5_kernel(const float* __restrict__ w, unsigned short* __restrict__ Wp, int M)
{
    int idx = blockIdx.x * 256 + threadIdx.x;
    if (idx >= M * 6400) return;
    int co = idx / 6400, k = idx % 6400;
    int tap = k >> 8, ci = k & 255;
    Wp[idx] = f2bf(w[((size_t)co * 256 + ci) * 25 + tap]);
}

// ---------------------------------------------------- transpose-cast to [img][px][128]
// optional rgate: multiplies by zr[img][128+ci][px] (builds r*h directly)
__global__ __launch_bounds__(256) void tc_kernel(
    const float* __restrict__ src, const float* __restrict__ rgate,
    unsigned short* __restrict__ dst)
{
    __shared__ float tile[128][65];
    int img = blockIdx.y, px0 = blockIdx.x * 64, t = threadIdx.x;
    #pragma unroll
    for (int i = 0; i < 32; ++i) {
        int e = i * 256 + t; int ci = e >> 6; int px = e & 63;
        float v = src[((size_t)img * 128 + ci) * 576 + px0 + px];
        if (rgate) v *= rgate[((size_t)img * 256 + 128 + ci) * 576 + px0 + px];
        tile[ci][px] = v;
    }
    __syncthreads();
    #pragma unroll
    for (int i = 0; i < 32; ++i) {
        int e = i * 256 + t; int px = e >> 7; int ci = e & 127;
        dst[((size_t)img * 576 + px0 + px) * 128 + ci] = f2bf(tile[ci][px]);
    }
}

// ------------------------------------------------------ MFMA implicit-GEMM conv
// block: 128 co x 32 px, 4 waves (wave = 64co x 16px = 4 mfma tiles)
// k-order: tap*CIN + ci ; A = Wp rows (global b128), B = windowed LDS (b128)
template<int TAPS, int R, int CIN>
__global__ __launch_bounds__(256) void conv_mfma(
    const unsigned short* __restrict__ srcA,  // [10][576][128] bf16 (ci<128)
    const unsigned short* __restrict__ srcB,  // [10][576][128] bf16 (ci>=128)
    const unsigned short* __restrict__ Wp,    // [M][TAPS*CIN] bf16
    const float* __restrict__ b0, const float* __restrict__ b1, const float* __restrict__ b2,
    float* __restrict__ o0, float* __restrict__ o1, float* __restrict__ o2,
    int act)
{
    constexpr int KD   = 2 * R + 1;
    constexpr int WR   = 3 + 2 * R;         // rows in window (32px span <=3 rows)
    constexpr int WC   = 24 + 2 * R;
    constexpr int NPOS = WR * WC;
    constexpr int KTOT = TAPS * CIN;
    __shared__ __align__(16) unsigned short Xs[NPOS * 32];

    int img = blockIdx.z;
    int cgb = blockIdx.y;                    // 128-co group
    int pxb = blockIdx.x;                    // 32-px tile
    int t = threadIdx.x;
    int wave = t >> 6, lane = t & 63;
    int cgw = wave & 1, pgw = wave >> 1;
    int coBase = cgb * 128 + cgw * 64;
    int px0w = pxb * 32 + pgw * 16;
    int r0 = (pxb * 32) / 24;
    int quad = lane >> 4;

    int px = px0w + (lane & 15);
    int prow = px / 24, pcol = px % 24;
    int posBase = (prow - r0 + R) * WC + pcol + R;

    v4f acc[4];
    #pragma unroll
    for (int c = 0; c < 4; ++c)
        #pragma unroll
        for (int r = 0; r < 4; ++r) acc[c][r] = 0.f;

    for (int ci0 = 0; ci0 < CIN; ci0 += 32) {
        __syncthreads();
        for (int idx = t; idx < NPOS * 4; idx += 256) {
            int pos = idx >> 2, gr = idx & 3;
            int wr = pos / WC, wc = pos % WC;
            int grow = r0 - R + wr, gcol = wc - R;
            v8s val;
            if (grow >= 0 && grow < 24 && gcol >= 0 && gcol < 24) {
                int ci = ci0 + gr * 8;
                const unsigned short* sp = (ci < 128)
                    ? srcA + (((size_t)img * 576 + grow * 24 + gcol) * 128 + ci)
                    : srcB + (((size_t)img * 576 + grow * 24 + gcol) * 128 + (ci - 128));
                val = *(const v8s*)sp;
            } else {
                #pragma unroll
                for (int j = 0; j < 8; ++j) val[j] = 0;
            }
            *(v8s*)&Xs[pos * 32 + gr * 8] = val;
        }
        __syncthreads();

        const unsigned short* wB = Wp + (size_t)(coBase + (lane & 15)) * KTOT + ci0 + quad * 8;
        #pragma unroll
        for (int tap = 0; tap < TAPS; ++tap) {
            int dy = tap / KD - R, dx = tap % KD - R;
            v8s b = *(const v8s*)&Xs[(posBase + dy * WC + dx) * 32 + quad * 8];
            #pragma unroll
            for (int c = 0; c < 4; ++c) {
                v8s a = *(const v8s*)(wB + (size_t)c * 16 * KTOT + tap * CIN);
                acc[c] = __builtin_amdgcn_mfma_f32_16x16x32_bf16(a, b, acc[c], 0, 0, 0);
            }
        }
    }

    int rowq = quad * 4;
    #pragma unroll
    for (int c = 0; c < 4; ++c) {
        #pragma unroll
        for (int r = 0; r < 4; ++r) {
            int co = coBase + c * 16 + rowq + r;
            float v = acc[c][r];
            if (act == 0) {
                int which = co >> 7, cl = co & 127;
                const float* bp = (which == 0) ? b0 : (which == 1) ? b1 : b2;
                float* op = (which == 0) ? o0 : (which == 1) ? o1 : o2;
                op[((size_t)img * 128 + cl) * 576 + px] = v + bp[cl];
            } else if (act == 1) {
                v += b0[co];
                o0[((size_t)img * 256 + co) * 576 + px] = 1.f / (1.f + __expf(-v));
            } else {
                v += b0[co];
                o0[((size_t)img * 128 + co) * 576 + px] = tanhf(v);
            }
        }
    }
}

// ---------------------------------------------------------------- yt = Wc @ h
__global__ __launch_bounds__(576) void yt_kernel(
    const float* __restrict__ h, const float* __restrict__ Wc, float* __restrict__ yt)
{
    int img = blockIdx.x, co = blockIdx.y, t = threadIdx.x;
    const float* wrow = Wc + (size_t)co * C_;
    const float* hp = h + (size_t)img * C_ * N_;
    float acc = 0.f;
    for (int d = 0; d < C_; ++d) acc += wrow[d] * hp[d * N_ + t];
    yt[((size_t)img * C_ + co) * N_ + t] = acc;
}

// ------------------------------------------------- fused attention (both paths)
__global__ __launch_bounds__(576) void attn_kernel(
    const float* __restrict__ Q, const float* __restrict__ K, const float* __restrict__ V,
    float* __restrict__ Of, unsigned short* __restrict__ Oh,
    const float* __restrict__ addsrc, const float* __restrict__ scale_ptr, int mode)
{
    __shared__ float qs[C_ * 16];
    __shared__ float E[16 * 577];
    int t = threadIdx.x;
    int n0 = blockIdx.x * 16;
    int p = blockIdx.y;
    int qimg, kimg, vimg;
    if (mode == 0) { qimg = kimg = vimg = p; }
    else {
        int b = p & 1; int ij = p >> 1; int i = ij >> 2; int jj = ij & 3;
        int j = jj + (jj >= i ? 1 : 0);
        qimg = i * B_ + b; kimg = j * B_ + b; vimg = kimg;
    }
    const float* Qp = Q + (size_t)qimg * C_ * N_;
    const float* Kp = K + (size_t)kimg * C_ * N_;
    const float* Vp = V + (size_t)vimg * C_ * N_;

    for (int idx = t; idx < C_ * 16; idx += 576) {
        int c = idx >> 4, r = idx & 15;
        qs[idx] = Qp[c * N_ + n0 + r];
    }
    __syncthreads();
    {
        float acc[16];
        #pragma unroll
        for (int r = 0; r < 16; ++r) acc[r] = 0.f;
        int m = t;
        for (int c = 0; c < C_; ++c) {
            float kv = Kp[c * N_ + m];
            #pragma unroll
            for (int r = 0; r < 16; ++r) acc[r] += qs[c * 16 + r] * kv;
        }
        #pragma unroll
        for (int r = 0; r < 16; ++r) E[r * 577 + m] = acc[r];
    }
    __syncthreads();
    {
        int wave = t >> 6, lane = t & 63;
        for (int r = wave; r < 16; r += 9) {
            float v[9];
            float mx = -1e30f;
            #pragma unroll
            for (int k = 0; k < 9; ++k) { v[k] = E[r * 577 + lane + 64 * k]; mx = fmaxf(mx, v[k]); }
            #pragma unroll
            for (int off = 32; off > 0; off >>= 1) mx = fmaxf(mx, __shfl_xor(mx, off));
            float sum = 0.f;
            #pragma unroll
            for (int k = 0; k < 9; ++k) { v[k] = __expf(v[k] - mx); sum += v[k]; }
            #pragma unroll
            for (int off = 32; off > 0; off >>= 1) sum += __shfl_xor(sum, off);
            float inv = 1.f / sum;
            #pragma unroll
            for (int k = 0; k < 9; ++k) E[r * 577 + lane + 64 * k] = v[k] * inv;
        }
    }
    __syncthreads();
    if (t < 512) {
        int c = t >> 2, rr = t & 3;
        float acc[4] = {0.f, 0.f, 0.f, 0.f};
        const float* vrow = Vp + (size_t)c * N_;
        for (int m = 0; m < N_; ++m) {
            float vv = vrow[m];
            #pragma unroll
            for (int k = 0; k < 4; ++k) acc[k] += vv * E[(rr * 4 + k) * 577 + m];
        }
        if (mode == 0) {
            float scale = scale_ptr[0];
            float* op = Of + ((size_t)p * C_ + c) * N_ + n0 + rr * 4;
            const float* ap = addsrc + ((size_t)p * C_ + c) * N_ + n0 + rr * 4;
            #pragma unroll
            for (int k = 0; k < 4; ++k) op[k] = scale * acc[k] + ap[k];
        } else {
            unsigned short* op = Oh + ((size_t)p * C_ + c) * N_ + n0 + rr * 4;
            #pragma unroll
            for (int k = 0; k < 4; ++k) op[k] = f2bf(acc[k]);
        }
    }
}

// ------------------------------------- window sums for analytic gate-conv mean
__global__ __launch_bounds__(64) void wsum_kernel(
    const unsigned short* __restrict__ mji, float* __restrict__ wsum)
{
    int pair = blockIdx.x, ci = blockIdx.y, lane = threadIdx.x;
    const unsigned short* p = mji + ((size_t)pair * C_ + ci) * N_;
    float T=0, R0=0, R23=0, Cl=0, Cr=0, c00=0, c0w=0, ch0=0, chw=0;
    for (int i = lane; i < N_; i += 64) {
        float v = bf2f(p[i]);
        int r = i / 24, cc = i % 24;
        T += v;
        if (r == 0)  R0  += v;
        if (r == 23) R23 += v;
        if (cc == 0)  Cl += v;
        if (cc == 23) Cr += v;
        if (i == 0)   c00 = v;
        if (i == 23)  c0w = v;
        if (i == 552) ch0 = v;
        if (i == 575) chw = v;
    }
    #pragma unroll
    for (int off = 32; off > 0; off >>= 1) {
        T  += __shfl_xor(T, off);  R0 += __shfl_xor(R0, off);  R23 += __shfl_xor(R23, off);
        Cl += __shfl_xor(Cl, off); Cr += __shfl_xor(Cr, off);
        c00 += __shfl_xor(c00, off); c0w += __shfl_xor(c0w, off);
        ch0 += __shfl_xor(ch0, off); chw += __shfl_xor(chw, off);
    }
    if (lane == 0) {
        float rowsub[3] = {R23, 0.f, R0};
        float colsub[3] = {Cr,  0.f, Cl};
        float corner[9] = {chw, 0.f, ch0,  0.f, 0.f, 0.f,  c0w, 0.f, c00};
        float* o = wsum + ((size_t)pair * C_ + ci) * 9;
        #pragma unroll
        for (int ky = 0; ky < 3; ++ky)
            #pragma unroll
            for (int kx = 0; kx < 3; ++kx)
                o[ky * 3 + kx] = T - rowsub[ky] - colsub[kx] + corner[ky * 3 + kx];
    }
}

__global__ __launch_bounds__(128) void g_kernel(
    const float* __restrict__ wsum, const float* __restrict__ Wg,
    const float* __restrict__ Wgb, float* __restrict__ g)
{
    __shared__ float sw[C_ * 9];
    int pair = blockIdx.x; int co = threadIdx.x;
    for (int i = co; i < C_ * 9; i += 128) sw[i] = wsum[(size_t)pair * C_ * 9 + i];
    __syncthreads();
    const float* w = Wg + (size_t)co * C_ * 9;
    float acc = 0.f;
    for (int i = 0; i < C_ * 9; ++i) acc += w[i] * sw[i];
    float m = acc * (1.f / 576.f) + Wgb[co];
    g[pair * C_ + co] = 1.f / (1.f + __expf(-m));
}

__global__ void msg_kernel(
    const float* __restrict__ eii, const unsigned short* __restrict__ mji,
    const float* __restrict__ g, const float* __restrict__ bn_gamma,
    const float* __restrict__ bn_beta, const float* __restrict__ intra_w,
    const float* __restrict__ inter_w, float* __restrict__ msg)
{
    int e = blockIdx.x * blockDim.x + threadIdx.x;
    if (e >= SB * C_ * N_) return;
    int n = e % N_;
    int c = (e / N_) % C_;
    int img = e / (N_ * C_);
    int s = img >> 1, b = img & 1;
    float scale = bn_gamma[c] * rsqrtf(1.f + 1e-5f);
    float acc = 0.f;
    #pragma unroll
    for (int jj = 0; jj < 4; ++jj) {
        int pidx = (s * 4 + jj) * 2 + b;
        acc += g[pidx * C_ + c] * bf2f(mji[((size_t)pidx * C_ + c) * N_ + n]);
    }
    float inter = scale * acc + 4.f * bn_beta[c];
    msg[e] = intra_w[0] * eii[e] + inter_w[0] * inter;
}

__global__ void update_kernel(const float* __restrict__ zr, const float* __restrict__ hhat,
                              const float* __restrict__ h, float* __restrict__ out)
{
    int e = blockIdx.x * blockDim.x + threadIdx.x;
    if (e >= SB * C_ * N_) return;
    int n = e % N_;
    int c = (e / N_) % C_;
    int img = e / (N_ * C_);
    float z = zr[((size_t)img * C2 + c) * N_ + n];
    out[e] = (2.f - z) * h[e] + z * hhat[e];
}

// ------------------------------------------------------------------- launcher
extern "C" void kernel_launch(void* const* d_in, const int* in_sizes, int n_in,
                              void* d_out, int out_size, void* d_ws, size_t ws_size,
                              hipStream_t stream)
{
    const float* x      = (const float*)d_in[0];
    const float* Wf_w   = (const float*)d_in[1];
    const float* Wf_b   = (const float*)d_in[2];
    const float* Wh_w   = (const float*)d_in[3];
    const float* Wh_b   = (const float*)d_in[4];
    const float* Wl_w   = (const float*)d_in[5];
    const float* Wl_b   = (const float*)d_in[6];
    const float* alpha  = (const float*)d_in[7];
    const float* Wc     = (const float*)d_in[8];
    const float* Wg_w   = (const float*)d_in[9];
    const float* Wg_b   = (const float*)d_in[10];
    const float* bng    = (const float*)d_in[11];
    const float* bnb    = (const float*)d_in[12];
    const float* zr_w   = (const float*)d_in[13];
    const float* zr_b   = (const float*)d_in[14];
    const float* gh_w   = (const float*)d_in[15];
    const float* gh_b   = (const float*)d_in[16];
    const float* intraw = (const float*)d_in[17];
    const float* interw = (const float*)d_in[18];
    float* outp = (float*)d_out;

    float* f = (float*)d_ws;
    const size_t SZ = (size_t)SB * C_ * N_;
    float* hbuf  = f; f += SZ;
    float* ft    = f; f += SZ;
    float* ht    = f; f += SZ;
    float* lt    = f; f += SZ;
    float* eii   = f; f += SZ;
    float* yt    = f; f += SZ;          // reused as hhat after inter-attn
    float* msg   = f; f += SZ;
    float* zr    = f; f += (size_t)SB * C2 * N_;
    float* wsumb = f; f += (size_t)NPAIR * C_ * 9;
    float* gbuf  = f; f += (size_t)NPAIR * C_;
    unsigned short* mji16  = (unsigned short*)f; f += (size_t)NPAIR * C_ * N_ / 2;
    unsigned short* hT16   = (unsigned short*)f; f += SZ / 2;
    unsigned short* msgT16 = (unsigned short*)f; f += SZ / 2;
    unsigned short* rhbT16 = (unsigned short*)f; f += SZ / 2;
    unsigned short* Wp3    = (unsigned short*)f; f += (size_t)384 * 1152 / 2;
    unsigned short* Wpzr   = (unsigned short*)f; f += (size_t)256 * 6400 / 2;
    unsigned short* Wph    = (unsigned short*)f; f += (size_t)128 * 6400 / 2;

    const int NELEM = SB * C_ * N_;
    dim3 eb((NELEM + 255) / 256);

    pack3_kernel<<<(384 * 1152 + 255) / 256, 256, 0, stream>>>(Wf_w, Wh_w, Wl_w, Wp3);
    pack5_kernel<<<(256 * 6400 + 255) / 256, 256, 0, stream>>>(zr_w, Wpzr, 256);
    pack5_kernel<<<(128 * 6400 + 255) / 256, 256, 0, stream>>>(gh_w, Wph, 128);

    const float* hcur = x;
    for (int it = 0; it < 3; ++it) {
        float* hout = (it == 2) ? outp : hbuf;
        float* hhat = yt;

        tc_kernel<<<dim3(9, SB), 256, 0, stream>>>(hcur, nullptr, hT16);
        conv_mfma<9, 1, 128><<<dim3(18, 3, SB), 256, 0, stream>>>(
            hT16, hT16, Wp3, Wf_b, Wh_b, Wl_b, ft, ht, lt, 0);
        attn_kernel<<<dim3(36, SB), 576, 0, stream>>>(ft, ht, lt, eii, nullptr, hcur, alpha, 0);
        yt_kernel<<<dim3(SB, C_), 576, 0, stream>>>(hcur, Wc, yt);
        attn_kernel<<<dim3(36, NPAIR), 576, 0, stream>>>(hcur, yt, hcur, nullptr, mji16, nullptr, nullptr, 1);
        wsum_kernel<<<dim3(NPAIR, C_), 64, 0, stream>>>(mji16, wsumb);
        g_kernel<<<NPAIR, 128, 0, stream>>>(wsumb, Wg_w, Wg_b, gbuf);
        msg_kernel<<<eb, 256, 0, stream>>>(eii, mji16, gbuf, bng, bnb, intraw, interw, msg);
        tc_kernel<<<dim3(9, SB), 256, 0, stream>>>(msg, nullptr, msgT16);
        conv_mfma<25, 2, 256><<<dim3(18, 2, SB), 256, 0, stream>>>(
            msgT16, hT16, Wpzr, zr_b, nullptr, nullptr, zr, nullptr, nullptr, 1);
        tc_kernel<<<dim3(9, SB), 256, 0, stream>>>(hcur, zr, rhbT16);
        conv_mfma<25, 2, 256><<<dim3(18, 1, SB), 256, 0, stream>>>(
            msgT16, rhbT16, Wph, gh_b, nullptr, nullptr, hhat, nullptr, nullptr, 2);
        update_kernel<<<eb, 256, 0, stream>>>(zr, hhat, hcur, hout);
        hcur = hout;
    }
}

// Round 3
// 1631.850 us; speedup vs baseline: 4.5578x; 1.3130x over previous
//
#include <hip/hip_runtime.h>
#include <math.h>

#define S_  5
#define B_  2
#define C_  128
#define N_  576
#define SB  10
#define NPAIR 40
#define C2  256

typedef short v8s __attribute__((ext_vector_type(8)));
typedef float v4f __attribute__((ext_vector_type(4)));

__device__ __forceinline__ unsigned short f2bf(float f) {
    union { float f; unsigned u; } v; v.f = f;
    unsigned r = (v.u + 0x7FFF + ((v.u >> 16) & 1)) >> 16;
    return (unsigned short)r;
}
__device__ __forceinline__ float bf2f(unsigned short h) {
    union { unsigned u; float f; } v; v.u = ((unsigned)h) << 16;
    return v.f;
}

// ------------------------------------------------------------------ weight packs
__global__ void pack3_kernel(const float* __restrict__ wf, const float* __restrict__ wh,
                             const float* __restrict__ wl, unsigned short* __restrict__ Wp3)
{
    int idx = blockIdx.x * 256 + threadIdx.x;
    if (idx >= 384 * 1152) return;
    int co = idx / 1152, k = idx % 1152;
    int tap = k >> 7, ci = k & 127;
    const float* w = (co < 128) ? wf : (co < 256) ? wh : wl;
    int c = co & 127;
    Wp3[idx] = f2bf(w[((size_t)c * 128 + ci) * 9 + tap]);
}
__global__ void pack5_kernel(const float* __restrict__ w, unsigned short* __restrict__ Wp, int M)
{
    int idx = blockIdx.x * 256 + threadIdx.x;
    if (idx >= M * 6400) return;
    int co = idx / 6400, k = idx % 6400;
    int tap = k >> 8, ci = k & 255;
    Wp[idx] = f2bf(w[((size_t)co * 256 + ci) * 25 + tap]);
}
__global__ void packWc_kernel(const float* __restrict__ w, unsigned short* __restrict__ o)
{
    int idx = blockIdx.x * 256 + threadIdx.x;
    if (idx < 128 * 128) o[idx] = f2bf(w[idx]);
}

// ---------------------------------------------- transpose-cast: [c][px] f32 -> [px][c] bf16
// optional rgate multiplies by zr[img][128+ci][px]; optional dst2 = bf16 [c][px]
__global__ __launch_bounds__(256) void tc_kernel(
    const float* __restrict__ src, const float* __restrict__ rgate,
    unsigned short* __restrict__ dst, unsigned short* __restrict__ dst2)
{
    __shared__ float tile[128][65];
    int img = blockIdx.y, px0 = blockIdx.x * 64, t = threadIdx.x;
    #pragma unroll
    for (int i = 0; i < 32; ++i) {
        int e = i * 256 + t; int ci = e >> 6; int px = e & 63;
        float v = src[((size_t)img * 128 + ci) * 576 + px0 + px];
        if (rgate) v *= rgate[((size_t)img * 256 + 128 + ci) * 576 + px0 + px];
        tile[ci][px] = v;
        if (dst2) dst2[((size_t)img * 128 + ci) * 576 + px0 + px] = f2bf(v);
    }
    __syncthreads();
    #pragma unroll
    for (int i = 0; i < 32; ++i) {
        int e = i * 256 + t; int px = e >> 7; int ci = e & 127;
        dst[((size_t)img * 576 + px0 + px) * 128 + ci] = f2bf(tile[ci][px]);
    }
}

// ------------------------------------------------------ MFMA implicit-GEMM conv
// LDS ci-chunk placement XOR-swizzled: slot = gr ^ ((pos>>1)&3) -> conflict-free b128 reads
template<int TAPS, int R, int CIN>
__global__ __launch_bounds__(256) void conv_mfma(
    const unsigned short* __restrict__ srcA, const unsigned short* __restrict__ srcB,
    const unsigned short* __restrict__ Wp,
    const float* __restrict__ b0, const float* __restrict__ b1, const float* __restrict__ b2,
    float* __restrict__ o0,
    unsigned short* __restrict__ t0, unsigned short* __restrict__ t1,
    unsigned short* __restrict__ t2, int act)
{
    constexpr int KD   = 2 * R + 1;
    constexpr int WR   = 3 + 2 * R;
    constexpr int WC   = 24 + 2 * R;
    constexpr int NPOS = WR * WC;
    constexpr int KTOT = TAPS * CIN;
    __shared__ __align__(16) unsigned short Xs[NPOS * 32];

    int img = blockIdx.z;
    int cgb = blockIdx.y;
    int pxb = blockIdx.x;
    int t = threadIdx.x;
    int wave = t >> 6, lane = t & 63;
    int cgw = wave & 1, pgw = wave >> 1;
    int coBase = cgb * 128 + cgw * 64;
    int px0w = pxb * 32 + pgw * 16;
    int r0 = (pxb * 32) / 24;
    int quad = lane >> 4;

    int px = px0w + (lane & 15);
    int prow = px / 24, pcol = px % 24;
    int posBase = (prow - r0 + R) * WC + pcol + R;

    v4f acc[4];
    #pragma unroll
    for (int c = 0; c < 4; ++c)
        #pragma unroll
        for (int r = 0; r < 4; ++r) acc[c][r] = 0.f;

    for (int ci0 = 0; ci0 < CIN; ci0 += 32) {
        __syncthreads();
        for (int idx = t; idx < NPOS * 4; idx += 256) {
            int pos = idx >> 2, gr = idx & 3;
            int wr = pos / WC, wc = pos % WC;
            int grow = r0 - R + wr, gcol = wc - R;
            v8s val;
            if (grow >= 0 && grow < 24 && gcol >= 0 && gcol < 24) {
                int ci = ci0 + gr * 8;
                const unsigned short* sp = (ci < 128)
                    ? srcA + (((size_t)img * 576 + grow * 24 + gcol) * 128 + ci)
                    : srcB + (((size_t)img * 576 + grow * 24 + gcol) * 128 + (ci - 128));
                val = *(const v8s*)sp;
            } else {
                #pragma unroll
                for (int j = 0; j < 8; ++j) val[j] = 0;
            }
            int sw = (gr ^ ((pos >> 1) & 3)) << 3;
            *(v8s*)&Xs[pos * 32 + sw] = val;
        }
        __syncthreads();

        const unsigned short* wB = Wp + (size_t)(coBase + (lane & 15)) * KTOT + ci0 + quad * 8;
        #pragma unroll
        for (int tap = 0; tap < TAPS; ++tap) {
            int dy = tap / KD - R, dx = tap % KD - R;
            int pos = posBase + dy * WC + dx;
            int sw = (quad ^ ((pos >> 1) & 3)) << 3;
            v8s b = *(const v8s*)&Xs[pos * 32 + sw];
            #pragma unroll
            for (int c = 0; c < 4; ++c) {
                v8s a = *(const v8s*)(wB + (size_t)c * 16 * KTOT + tap * CIN);
                acc[c] = __builtin_amdgcn_mfma_f32_16x16x32_bf16(a, b, acc[c], 0, 0, 0);
            }
        }
    }

    int rowq = quad * 4;
    #pragma unroll
    for (int c = 0; c < 4; ++c) {
        #pragma unroll
        for (int r = 0; r < 4; ++r) {
            int co = coBase + c * 16 + rowq + r;
            float v = acc[c][r];
            if (act == 0) {
                int which = co >> 7, cl = co & 127;
                const float* bp = (which == 0) ? b0 : (which == 1) ? b1 : b2;
                float v2 = v + bp[cl];
                if (which == 0)      t0[((size_t)img * 576 + px) * 128 + cl] = f2bf(v2);
                else if (which == 1) t1[((size_t)img * 576 + px) * 128 + cl] = f2bf(v2);
                else                 t2[((size_t)img * 128 + cl) * 576 + px] = f2bf(v2);
            } else if (act == 1) {
                v += b0[co];
                o0[((size_t)img * 256 + co) * 576 + px] = 1.f / (1.f + __expf(-v));
            } else {
                v += b0[co];
                o0[((size_t)img * 128 + co) * 576 + px] = tanhf(v);
            }
        }
    }
}

// ---------------------------------------------------------------- yt (MFMA)
// ytT[img][n][co] bf16 = (Wc @ h)^T ; A = Wc rows, B = hT
__global__ __launch_bounds__(256) void yt_mfma(
    const unsigned short* __restrict__ hT, const unsigned short* __restrict__ Wcb,
    unsigned short* __restrict__ ytT)
{
    int t = threadIdx.x, wave = t >> 6, lane = t & 63;
    int q = lane >> 4, l15 = lane & 15;
    int n0 = blockIdx.x * 16, img = blockIdx.y;
    v4f acc[2];
    #pragma unroll
    for (int ct = 0; ct < 2; ++ct)
        #pragma unroll
        for (int r = 0; r < 4; ++r) acc[ct][r] = 0.f;
    #pragma unroll
    for (int kk = 0; kk < 4; ++kk) {
        v8s b = *(const v8s*)(hT + ((size_t)img * 576 + n0 + l15) * 128 + kk * 32 + q * 8);
        #pragma unroll
        for (int ct = 0; ct < 2; ++ct) {
            v8s a = *(const v8s*)(Wcb + (size_t)((wave * 2 + ct) * 16 + l15) * 128 + kk * 32 + q * 8);
            acc[ct] = __builtin_amdgcn_mfma_f32_16x16x32_bf16(a, b, acc[ct], 0, 0, 0);
        }
    }
    #pragma unroll
    for (int ct = 0; ct < 2; ++ct) {
        unsigned short* op = ytT + ((size_t)img * 576 + n0 + l15) * 128 + (wave * 2 + ct) * 16 + q * 4;
        #pragma unroll
        for (int r = 0; r < 4; ++r) op[r] = f2bf(acc[ct][r]);
    }
}

// ---------------------------------------------------- MFMA flash attention
// MODE 0: O = alpha*softmax(Q^T K)V^T + addsrc (f32)   MODE 1: O = softmax(.)V^T (bf16)
template<int MODE>
__global__ __launch_bounds__(256) void attn_mfma(
    const unsigned short* __restrict__ QT, const unsigned short* __restrict__ KT,
    const unsigned short* __restrict__ Vc, float* __restrict__ Of,
    unsigned short* __restrict__ Oh, const float* __restrict__ addsrc,
    const float* __restrict__ alpha)
{
    __shared__ __align__(16) unsigned short P[16 * 576];
    __shared__ float redmx[4][16];
    __shared__ float redsm[4][16];
    int t = threadIdx.x;
    int wave = t >> 6, lane = t & 63;
    int q = lane >> 4, l15 = lane & 15;
    int n0 = blockIdx.x * 16;
    int p = blockIdx.y;
    int qimg, kimg;
    if (MODE == 0) { qimg = p; kimg = p; }
    else {
        int b = p & 1; int ij = p >> 1; int i = ij >> 2; int jj = ij & 3;
        int j = jj + (jj >= i ? 1 : 0);
        qimg = i * 2 + b; kimg = j * 2 + b;
    }
    const unsigned short* Qp = QT + ((size_t)qimg * 576 + n0) * 128;
    const unsigned short* Kp = KT + (size_t)kimg * 576 * 128;
    const unsigned short* Vp = Vc + (size_t)kimg * 128 * 576;

    v8s aq[4];
    #pragma unroll
    for (int kk = 0; kk < 4; ++kk)
        aq[kk] = *(const v8s*)(Qp + (size_t)l15 * 128 + kk * 32 + q * 8);

    v4f S[9];
    #pragma unroll
    for (int i = 0; i < 9; ++i)
        #pragma unroll
        for (int r = 0; r < 4; ++r) S[i][r] = 0.f;

    #pragma unroll
    for (int i = 0; i < 9; ++i) {
        int m0 = (wave * 9 + i) * 16;
        #pragma unroll
        for (int kk = 0; kk < 4; ++kk) {
            v8s b = *(const v8s*)(Kp + ((size_t)(m0 + l15)) * 128 + kk * 32 + q * 8);
            S[i] = __builtin_amdgcn_mfma_f32_16x16x32_bf16(aq[kk], b, S[i], 0, 0, 0);
        }
    }

    // row max (rows = q*4+r, cols within wave's 9 m-tiles)
    float mx[4];
    #pragma unroll
    for (int r = 0; r < 4; ++r) {
        float m = S[0][r];
        #pragma unroll
        for (int i = 1; i < 9; ++i) m = fmaxf(m, S[i][r]);
        #pragma unroll
        for (int off = 1; off < 16; off <<= 1) m = fmaxf(m, __shfl_xor(m, off));
        mx[r] = m;
    }
    if (l15 == 0) {
        #pragma unroll
        for (int r = 0; r < 4; ++r) redmx[wave][q * 4 + r] = mx[r];
    }
    __syncthreads();
    float sum[4];
    #pragma unroll
    for (int r = 0; r < 4; ++r) {
        float g = fmaxf(fmaxf(redmx[0][q * 4 + r], redmx[1][q * 4 + r]),
                        fmaxf(redmx[2][q * 4 + r], redmx[3][q * 4 + r]));
        float s = 0.f;
        #pragma unroll
        for (int i = 0; i < 9; ++i) { float e = __expf(S[i][r] - g); S[i][r] = e; s += e; }
        #pragma unroll
        for (int off = 1; off < 16; off <<= 1) s += __shfl_xor(s, off);
        sum[r] = s;
    }
    if (l15 == 0) {
        #pragma unroll
        for (int r = 0; r < 4; ++r) redsm[wave][q * 4 + r] = sum[r];
    }
    // write unnormalized P, XOR-swizzled (chunk cm -> cm ^ (n&7))
    #pragma unroll
    for (int i = 0; i < 9; ++i) {
        int m = (wave * 9 + i) * 16 + l15;
        int cm = m >> 3, mo = m & 7;
        #pragma unroll
        for (int r = 0; r < 4; ++r) {
            int n = q * 4 + r;
            P[n * 576 + ((cm ^ (n & 7)) << 3) + mo] = f2bf(S[i][r]);
        }
    }
    __syncthreads();
    float inv[4];
    #pragma unroll
    for (int r = 0; r < 4; ++r)
        inv[r] = 1.f / (redsm[0][q * 4 + r] + redsm[1][q * 4 + r] +
                        redsm[2][q * 4 + r] + redsm[3][q * 4 + r]);

    // PV: O^T[n][c] ; A = P rows (LDS), B = V rows [c][m] (global)
    v4f o[2];
    #pragma unroll
    for (int ct = 0; ct < 2; ++ct)
        #pragma unroll
        for (int r = 0; r < 4; ++r) o[ct][r] = 0.f;

    for (int s = 0; s < 18; ++s) {
        int cm = s * 4 + q;
        v8s a = *(const v8s*)&P[l15 * 576 + ((cm ^ (l15 & 7)) << 3)];
        #pragma unroll
        for (int ct = 0; ct < 2; ++ct) {
            int c = (wave * 2 + ct) * 16 + l15;
            v8s b = *(const v8s*)(Vp + (size_t)c * 576 + s * 32 + q * 8);
            o[ct] = __builtin_amdgcn_mfma_f32_16x16x32_bf16(a, b, o[ct], 0, 0, 0);
        }
    }

    #pragma unroll
    for (int ct = 0; ct < 2; ++ct) {
        int c = (wave * 2 + ct) * 16 + l15;
        size_t base = ((size_t)p * 128 + c) * 576 + n0 + q * 4;
        if (MODE == 0) {
            float al = alpha[0];
            #pragma unroll
            for (int r = 0; r < 4; ++r)
                Of[base + r] = al * o[ct][r] * inv[r] + addsrc[base + r];
        } else {
            #pragma unroll
            for (int r = 0; r < 4; ++r)
                Oh[base + r] = f2bf(o[ct][r] * inv[r]);
        }
    }
}

// ------------------------------------- window sums for analytic gate-conv mean
__global__ __launch_bounds__(64) void wsum_kernel(
    const unsigned short* __restrict__ mji, float* __restrict__ wsum)
{
    int pair = blockIdx.x, ci = blockIdx.y, lane = threadIdx.x;
    const unsigned short* p = mji + ((size_t)pair * C_ + ci) * N_;
    float T=0, R0=0, R23=0, Cl=0, Cr=0, c00=0, c0w=0, ch0=0, chw=0;
    for (int i = lane; i < N_; i += 64) {
        float v = bf2f(p[i]);
        int r = i / 24, cc = i % 24;
        T += v;
        if (r == 0)  R0  += v;
        if (r == 23) R23 += v;
        if (cc == 0)  Cl += v;
        if (cc == 23) Cr += v;
        if (i == 0)   c00 = v;
        if (i == 23)  c0w = v;
        if (i == 552) ch0 = v;
        if (i == 575) chw = v;
    }
    #pragma unroll
    for (int off = 32; off > 0; off >>= 1) {
        T  += __shfl_xor(T, off);  R0 += __shfl_xor(R0, off);  R23 += __shfl_xor(R23, off);
        Cl += __shfl_xor(Cl, off); Cr += __shfl_xor(Cr, off);
        c00 += __shfl_xor(c00, off); c0w += __shfl_xor(c0w, off);
        ch0 += __shfl_xor(ch0, off); chw += __shfl_xor(chw, off);
    }
    if (lane == 0) {
        float rowsub[3] = {R23, 0.f, R0};
        float colsub[3] = {Cr,  0.f, Cl};
        float corner[9] = {chw, 0.f, ch0,  0.f, 0.f, 0.f,  c0w, 0.f, c00};
        float* o = wsum + ((size_t)pair * C_ + ci) * 9;
        #pragma unroll
        for (int ky = 0; ky < 3; ++ky)
            #pragma unroll
            for (int kx = 0; kx < 3; ++kx)
                o[ky * 3 + kx] = T - rowsub[ky] - colsub[kx] + corner[ky * 3 + kx];
    }
}

__global__ __launch_bounds__(128) void g_kernel(
    const float* __restrict__ wsum, const float* __restrict__ Wg,
    const float* __restrict__ Wgb, float* __restrict__ g)
{
    __shared__ float sw[C_ * 9];
    int pair = blockIdx.x; int co = threadIdx.x;
    for (int i = co; i < C_ * 9; i += 128) sw[i] = wsum[(size_t)pair * C_ * 9 + i];
    __syncthreads();
    const float* w = Wg + (size_t)co * C_ * 9;
    float acc = 0.f;
    for (int i = 0; i < C_ * 9; ++i) acc += w[i] * sw[i];
    float m = acc * (1.f / 576.f) + Wgb[co];
    g[pair * C_ + co] = 1.f / (1.f + __expf(-m));
}

__global__ void msg_kernel(
    const float* __restrict__ eii, const unsigned short* __restrict__ mji,
    const float* __restrict__ g, const float* __restrict__ bn_gamma,
    const float* __restrict__ bn_beta, const float* __restrict__ intra_w,
    const float* __restrict__ inter_w, float* __restrict__ msg)
{
    int e = blockIdx.x * blockDim.x + threadIdx.x;
    if (e >= SB * C_ * N_) return;
    int n = e % N_;
    int c = (e / N_) % C_;
    int img = e / (N_ * C_);
    int s = img >> 1, b = img & 1;
    float scale = bn_gamma[c] * rsqrtf(1.f + 1e-5f);
    float acc = 0.f;
    #pragma unroll
    for (int jj = 0; jj < 4; ++jj) {
        int pidx = (s * 4 + jj) * 2 + b;
        acc += g[pidx * C_ + c] * bf2f(mji[((size_t)pidx * C_ + c) * N_ + n]);
    }
    float inter = scale * acc + 4.f * bn_beta[c];
    msg[e] = intra_w[0] * eii[e] + inter_w[0] * inter;
}

__global__ void update_kernel(const float* __restrict__ zr, const float* __restrict__ hhat,
                              const float* __restrict__ h, float* __restrict__ out)
{
    int e = blockIdx.x * blockDim.x + threadIdx.x;
    if (e >= SB * C_ * N_) return;
    int n = e % N_;
    int c = (e / N_) % C_;
    int img = e / (N_ * C_);
    float z = zr[((size_t)img * C2 + c) * N_ + n];
    out[e] = (2.f - z) * h[e] + z * hhat[e];
}

// ------------------------------------------------------------------- launcher
extern "C" void kernel_launch(void* const* d_in, const int* in_sizes, int n_in,
                              void* d_out, int out_size, void* d_ws, size_t ws_size,
                              hipStream_t stream)
{
    const float* x      = (const float*)d_in[0];
    const float* Wf_w   = (const float*)d_in[1];
    const float* Wf_b   = (const float*)d_in[2];
    const float* Wh_w   = (const float*)d_in[3];
    const float* Wh_b   = (const float*)d_in[4];
    const float* Wl_w   = (const float*)d_in[5];
    const float* Wl_b   = (const float*)d_in[6];
    const float* alpha  = (const float*)d_in[7];
    const float* Wc     = (const float*)d_in[8];
    const float* Wg_w   = (const float*)d_in[9];
    const float* Wg_b   = (const float*)d_in[10];
    const float* bng    = (const float*)d_in[11];
    const float* bnb    = (const float*)d_in[12];
    const float* zr_w   = (const float*)d_in[13];
    const float* zr_b   = (const float*)d_in[14];
    const float* gh_w   = (const float*)d_in[15];
    const float* gh_b   = (const float*)d_in[16];
    const float* intraw = (const float*)d_in[17];
    const float* interw = (const float*)d_in[18];
    float* outp = (float*)d_out;

    float* f = (float*)d_ws;
    const size_t SZ = (size_t)SB * C_ * N_;
    float* hbuf  = f; f += SZ;
    float* eii   = f; f += SZ;
    float* msg   = f; f += SZ;
    float* hhat  = f; f += SZ;
    float* zr    = f; f += (size_t)SB * C2 * N_;
    float* wsumb = f; f += (size_t)NPAIR * C_ * 9;
    float* gbuf  = f; f += (size_t)NPAIR * C_;
    unsigned short* us = (unsigned short*)f;
    unsigned short* mji16  = us; us += (size_t)NPAIR * C_ * N_;
    unsigned short* hT16   = us; us += SZ;
    unsigned short* hc16   = us; us += SZ;
    unsigned short* msgT16 = us; us += SZ;
    unsigned short* rhbT16 = us; us += SZ;
    unsigned short* ftT    = us; us += SZ;
    unsigned short* htT    = us; us += SZ;
    unsigned short* lt16   = us; us += SZ;
    unsigned short* ytT    = us; us += SZ;
    unsigned short* Wp3    = us; us += (size_t)384 * 1152;
    unsigned short* Wpzr   = us; us += (size_t)256 * 6400;
    unsigned short* Wph    = us; us += (size_t)128 * 6400;
    unsigned short* Wcb    = us; us += (size_t)128 * 128;

    const int NELEM = SB * C_ * N_;
    dim3 eb((NELEM + 255) / 256);

    pack3_kernel<<<(384 * 1152 + 255) / 256, 256, 0, stream>>>(Wf_w, Wh_w, Wl_w, Wp3);
    pack5_kernel<<<(256 * 6400 + 255) / 256, 256, 0, stream>>>(zr_w, Wpzr, 256);
    pack5_kernel<<<(128 * 6400 + 255) / 256, 256, 0, stream>>>(gh_w, Wph, 128);
    packWc_kernel<<<64, 256, 0, stream>>>(Wc, Wcb);

    const float* hcur = x;
    for (int it = 0; it < 3; ++it) {
        float* hout = (it == 2) ? outp : hbuf;

        tc_kernel<<<dim3(9, SB), 256, 0, stream>>>(hcur, nullptr, hT16, hc16);
        conv_mfma<9, 1, 128><<<dim3(18, 3, SB), 256, 0, stream>>>(
            hT16, hT16, Wp3, Wf_b, Wh_b, Wl_b, nullptr, ftT, htT, lt16, 0);
        attn_mfma<0><<<dim3(36, SB), 256, 0, stream>>>(ftT, htT, lt16, eii, nullptr, hcur, alpha);
        yt_mfma<<<dim3(36, SB), 256, 0, stream>>>(hT16, Wcb, ytT);
        attn_mfma<1><<<dim3(36, NPAIR), 256, 0, stream>>>(hT16, ytT, hc16, nullptr, mji16, nullptr, nullptr);
        wsum_kernel<<<dim3(NPAIR, C_), 64, 0, stream>>>(mji16, wsumb);
        g_kernel<<<NPAIR, 128, 0, stream>>>(wsumb, Wg_w, Wg_b, gbuf);
        msg_kernel<<<eb, 256, 0, stream>>>(eii, mji16, gbuf, bng, bnb, intraw, interw, msg);
        tc_kernel<<<dim3(9, SB), 256, 0, stream>>>(msg, nullptr, msgT16, nullptr);
        conv_mfma<25, 2, 256><<<dim3(18, 2, SB), 256, 0, stream>>>(
            msgT16, hT16, Wpzr, zr_b, nullptr, nullptr, zr, nullptr, nullptr, nullptr, 1);
        tc_kernel<<<dim3(9, SB), 256, 0, stream>>>(hcur, zr, rhbT16, nullptr);
        conv_mfma<25, 2, 256><<<dim3(18, 1, SB), 256, 0, stream>>>(
            msgT16, rhbT16, Wph, gh_b, nullptr, nullptr, hhat, nullptr, nullptr, nullptr, 2);
        update_kernel<<<eb, 256, 0, stream>>>(zr, hhat, hcur, hout);
        hcur = hout;
    }
}